// Round 14
// baseline (292.353 us; speedup 1.0000x reference)
//
#include <hip/hip_runtime.h>
#include <math.h>

#define T_TOKENS 32768
#define HIDDEN   4096
#define NEXP     128
#define TM       64
#define BK       32
#define NSTAGE   (HIDDEN / BK)            // 128

// LDS (shorts): [Abuf0 12KB][Abuf1 12KB][Bbuf0 24KB][Bbuf1 24KB] = 72 KiB
// A plane (per buf): 2 rt-tiles x 2 ksteps x 64 lanes x 8 = 2048 shorts
// B chunk (per stage): 2 ksteps x 3 planes x 4 ct-tiles x 64 x 8 = 12288 shorts
#define A_BUF_SH      6144
#define B_BASE_SH     (2 * A_BUF_SH)      // 12288
#define B_BUF_SH      12288
#define LDS_SHORTS    (B_BASE_SH + 2 * B_BUF_SH)   // 36864 shorts = 72 KiB
#define B_BASE_BYTES  (B_BASE_SH * 2)
#define B_BUF_BYTES   (B_BUF_SH * 2)
#define A_PLANE_SH    2048
#define SC_STRIDE     129
#define B_CHUNK_BYTES B_BUF_BYTES
#define WS_BYTES ((size_t)NSTAGE * B_CHUNK_BYTES)  // 3 MiB

typedef short bf16x8 __attribute__((ext_vector_type(8)));
typedef short bf16x4 __attribute__((ext_vector_type(4)));
typedef float f32x16 __attribute__((ext_vector_type(16)));

__device__ __forceinline__ unsigned short f2bf(float f) {
    unsigned u = __float_as_uint(f);
    u += 0x7FFF + ((u >> 16) & 1);          // round-to-nearest-even
    return (unsigned short)(u >> 16);
}
__device__ __forceinline__ float bf2f(unsigned short h) {
    return __uint_as_float(((unsigned)h) << 16);
}
// 3-term bf16 cascade: x = b0 + b1 + b2 + delta, |delta| <= 2^-27 |x|
__device__ __forceinline__ void split3(float x, unsigned short& b0,
                                       unsigned short& b1, unsigned short& b2) {
    b0 = f2bf(x);
    float r1 = x - bf2f(b0);                // exact (Sterbenz)
    b1 = f2bf(r1);
    float r2 = r1 - bf2f(b1);               // exact
    b2 = f2bf(r2);
}

// ---- kernel 1: split w into 3 bf16 planes, fragment-major for 32x32x16.
// Fragment (s, kstep kk, plane p, ct-tile t, lane l) holds 8 bf16:
//   w[t*32 + (l&31)][s*32 + kk*16 + ((l>>5)&1)*8 + j]
// stored at ws16[(((s*2+kk)*12 + p*4 + t)*64 + l)*8].
// Per-stage chunk = 24 KB, a byte-exact linear image of the B LDS buffer.
__global__ __launch_bounds__(256) void presplit_w(
    const float* __restrict__ w, short* __restrict__ ws16)
{
    const int g  = blockIdx.x * 256 + threadIdx.x;   // 65536 total
    const int l  = g & 63;
    const int t  = (g >> 6) & 3;
    const int kk = (g >> 8) & 1;
    const int s  = g >> 9;                           // 0..127
    const int e  = t * 32 + (l & 31);
    const int kb = s * BK + kk * 16 + ((l >> 5) & 1) * 8;
    const float* src = w + (size_t)e * HIDDEN + kb;
    float4 v0 = *(const float4*)(src);
    float4 v1 = *(const float4*)(src + 4);
    float vv[8] = {v0.x, v0.y, v0.z, v0.w, v1.x, v1.y, v1.z, v1.w};
    unsigned short h0[8], h1[8], h2[8];
#pragma unroll
    for (int j = 0; j < 8; ++j) split3(vv[j], h0[j], h1[j], h2[j]);
    const size_t fb = ((size_t)(s * 2 + kk) * 12 + t) * 64 + l;  // plane 0 frag
    bf16x8 o0 = {(short)h0[0],(short)h0[1],(short)h0[2],(short)h0[3],
                 (short)h0[4],(short)h0[5],(short)h0[6],(short)h0[7]};
    bf16x8 o1 = {(short)h1[0],(short)h1[1],(short)h1[2],(short)h1[3],
                 (short)h1[4],(short)h1[5],(short)h1[6],(short)h1[7]};
    bf16x8 o2 = {(short)h2[0],(short)h2[1],(short)h2[2],(short)h2[3],
                 (short)h2[4],(short)h2[5],(short)h2[6],(short)h2[7]};
    *(bf16x8*)(ws16 + (fb + 0 * 4 * 64) * 8) = o0;   // plane stride = 4 tiles
    *(bf16x8*)(ws16 + (fb + 1 * 4 * 64) * 8) = o1;
    *(bf16x8*)(ws16 + (fb + 2 * 4 * 64) * 8) = o2;
}

// 512 threads = 8 waves; wave owns ONE 32tok x 32exp tile (rt = wid&1,
// ct = wid>>1). 32x32x16 MFMA: ~8.07cy/instr vs 2x 16x16x32 at 2x4.85cy
// (-17% MFMA pipe) and half the MFMA instruction count per body.
// Sync = R13's verified per-stage __syncthreads (full drain).
__global__ __launch_bounds__(512, 4) void glm4_router_mfma(
    const float* __restrict__ x, const short* __restrict__ wsplit,
    const float* __restrict__ bias, float* __restrict__ out)
{
    __shared__ __align__(16) short lds[LDS_SHORTS];

    const int tid  = threadIdx.x;
    const int wid  = tid >> 6;
    const int lane = tid & 63;
    const int rt   = wid & 1;               // token 32-tile: 0 or 1
    const int ct   = wid >> 1;              // expert 32-tile: 0..3
    const int tok_base = blockIdx.x * TM;

    // A staging: thread tid b64-writes shorts [tid*4..tid*4+3) of each plane.
    // Fragment f = tid>>1: rt_=f>>7, kk=(f>>6)&1, l=f&63;
    // row = rt_*32+(l&31); k-in-stage = kk*16 + ((l>>5)&1)*8 + (tid&1)*4.
    const int af   = tid >> 1;
    const int arow = (af >> 7) * 32 + (af & 31);
    const int akoff = (((af >> 6) & 1) * 16) + (((af >> 5) & 1) * 8) + (tid & 1) * 4;
    const float* xsrc = x + (size_t)(tok_base + arow) * HIDDEN + akoff;
    const int awr = tid * 4;                // shorts, within a plane

    f32x16 acc;             // one 32x32 tile, all 6 split-products
    double accd[16];        // fp64 running sum (fold every K=128)
#pragma unroll
    for (int v = 0; v < 16; ++v) { acc[v] = 0.0f; accd[v] = 0.0; }

#define GLDS_B(S, BUF) do {                                                    \
    const char* gsrc_ = (const char*)wsplit + (size_t)(S) * B_CHUNK_BYTES + tid * 16; \
    char* ldst_ = (char*)lds + B_BASE_BYTES + (BUF) * B_BUF_BYTES + tid * 16;  \
    __builtin_amdgcn_global_load_lds(                                          \
        (const __attribute__((address_space(1))) unsigned*)(gsrc_),            \
        (__attribute__((address_space(3))) unsigned*)(ldst_), 16, 0, 0);       \
    __builtin_amdgcn_global_load_lds(                                          \
        (const __attribute__((address_space(1))) unsigned*)(gsrc_ + 8192),     \
        (__attribute__((address_space(3))) unsigned*)(ldst_ + 8192), 16, 0, 0);\
    __builtin_amdgcn_global_load_lds(                                          \
        (const __attribute__((address_space(1))) unsigned*)(gsrc_ + 16384),    \
        (__attribute__((address_space(3))) unsigned*)(ldst_ + 16384), 16, 0, 0);\
} while (0)

#define SPLIT_A(XV, BUF) do {                                                  \
    unsigned short h0_[4], h1_[4], h2_[4];                                     \
    split3((XV).x, h0_[0], h1_[0], h2_[0]);                                    \
    split3((XV).y, h0_[1], h1_[1], h2_[1]);                                    \
    split3((XV).z, h0_[2], h1_[2], h2_[2]);                                    \
    split3((XV).w, h0_[3], h1_[3], h2_[3]);                                    \
    short* ab_ = &lds[(BUF) * A_BUF_SH + awr];                                 \
    *(bf16x4*)(ab_ + 0 * A_PLANE_SH) =                                         \
        (bf16x4){(short)h0_[0], (short)h0_[1], (short)h0_[2], (short)h0_[3]};  \
    *(bf16x4*)(ab_ + 1 * A_PLANE_SH) =                                         \
        (bf16x4){(short)h1_[0], (short)h1_[1], (short)h1_[2], (short)h1_[3]};  \
    *(bf16x4*)(ab_ + 2 * A_PLANE_SH) =                                         \
        (bf16x4){(short)h2_[0], (short)h2_[1], (short)h2_[2], (short)h2_[3]};  \
} while (0)

    // A frag read (plane p, kstep kk): lds[buf*A_BUF_SH + p*2048 + ((rt*2+kk)*64+lane)*8]
    // B frag read (plane p, kstep kk): lds[B_BASE + buf*B_BUF_SH + ((kk*12+p*4+ct)*64+lane)*8]
    // 6 products per kstep, per-acc order: a0b0, a0b1, a1b0, a0b2, a2b0, a1b1
#define MFMA_K(BUF, KK) do {                                                   \
    bf16x8 a0 = *(const bf16x8*)(&lds[(BUF) * A_BUF_SH + 0 * A_PLANE_SH        \
                                      + ((rt * 2 + (KK)) * 64 + lane) * 8]);   \
    bf16x8 a1 = *(const bf16x8*)(&lds[(BUF) * A_BUF_SH + 1 * A_PLANE_SH        \
                                      + ((rt * 2 + (KK)) * 64 + lane) * 8]);   \
    bf16x8 a2 = *(const bf16x8*)(&lds[(BUF) * A_BUF_SH + 2 * A_PLANE_SH        \
                                      + ((rt * 2 + (KK)) * 64 + lane) * 8]);   \
    bf16x8 b0 = *(const bf16x8*)(&lds[B_BASE_SH + (BUF) * B_BUF_SH             \
                                      + (((KK) * 12 + 0 * 4 + ct) * 64 + lane) * 8]); \
    bf16x8 b1 = *(const bf16x8*)(&lds[B_BASE_SH + (BUF) * B_BUF_SH             \
                                      + (((KK) * 12 + 1 * 4 + ct) * 64 + lane) * 8]); \
    bf16x8 b2 = *(const bf16x8*)(&lds[B_BASE_SH + (BUF) * B_BUF_SH             \
                                      + (((KK) * 12 + 2 * 4 + ct) * 64 + lane) * 8]); \
    __builtin_amdgcn_s_setprio(1);                                             \
    acc = __builtin_amdgcn_mfma_f32_32x32x16_bf16(a0, b0, acc, 0, 0, 0);       \
    acc = __builtin_amdgcn_mfma_f32_32x32x16_bf16(a0, b1, acc, 0, 0, 0);       \
    acc = __builtin_amdgcn_mfma_f32_32x32x16_bf16(a1, b0, acc, 0, 0, 0);       \
    acc = __builtin_amdgcn_mfma_f32_32x32x16_bf16(a0, b2, acc, 0, 0, 0);       \
    acc = __builtin_amdgcn_mfma_f32_32x32x16_bf16(a2, b0, acc, 0, 0, 0);       \
    acc = __builtin_amdgcn_mfma_f32_32x32x16_bf16(a1, b1, acc, 0, 0, 0);       \
    __builtin_amdgcn_s_setprio(0);                                             \
} while (0)

#define BODY(S, BUF, XC, XL) do {                                              \
    GLDS_B((S) + 1, (BUF) ^ 1);                                                \
    {                                                                          \
        int s2_ = (S) + 2; if (s2_ > NSTAGE - 1) s2_ = NSTAGE - 1;             \
        XL = *(const float4*)(xsrc + (size_t)s2_ * BK);                        \
    }                                                                          \
    MFMA_K(BUF, 0);                                                            \
    SPLIT_A(XC, (BUF) ^ 1);   /* VALU + ds_write between MFMA clusters */      \
    MFMA_K(BUF, 1);                                                            \
    if (((S) & 3) == 3) {                                                      \
        _Pragma("unroll")                                                      \
        for (int v = 0; v < 16; ++v) { accd[v] += (double)acc[v]; acc[v] = 0.0f; } \
    }                                                                          \
    __syncthreads();   /* full drain + barrier: verified-correct handoff */    \
} while (0)

    // prologue: fill buf0 with stage 0 (B glds + A split), prefetch x[1]
    float4 xA, xB;
    {
        float4 x0v = *(const float4*)(xsrc);
        GLDS_B(0, 0);
        xA = *(const float4*)(xsrc + BK);   // x[1]
        SPLIT_A(x0v, 0);
    }
    __syncthreads();

    for (int s = 0; s < NSTAGE - 2; s += 2) {
        BODY(s, 0, xA, xB);
        BODY(s + 1, 1, xB, xA);
    }
    BODY(NSTAGE - 2, 0, xA, xB);

    // tail: stage 127 from buf1 (fully staged; drained by the last barrier)
    MFMA_K(1, 0);
    MFMA_K(1, 1);
#pragma unroll
    for (int v = 0; v < 16; ++v) accd[v] += (double)acc[v];  // final fold

    // ---- epilogue: logits -> biased scores into LDS overlay (fp32) ----
    // C/D layout (m74/m101-verified): col = lane&31, row = (v&3)+8*(v>>2)+4*(lane>>5)
    __syncthreads();
    float* sc = (float*)lds;                       // [64][129] = 33 KB
#pragma unroll
    for (int v = 0; v < 16; ++v) {
        const int tokl = rt * 32 + (v & 3) + 8 * (v >> 2) + 4 * (lane >> 5);
        const int e    = ct * 32 + (lane & 31);
        const float lg = (float)accd[v];
        const float sg = (float)(1.0 / (1.0 + exp(-(double)lg)));
        sc[tokl * SC_STRIDE + e] = sg + bias[e];
    }
    __syncthreads();

    // ---- routing: one lane per token (wave 0) — verified logic ----
    if (tid < TM) {
        const float* scp = sc + tid * SC_STRIDE;

        float gsc[8];
#pragma unroll
        for (int g = 0; g < 8; ++g) {
            float m1 = -1e30f, m2 = -1e30f;
#pragma unroll
            for (int j = 0; j < 16; ++j) {
                const float v = scp[g * 16 + j];
                if (v > m1) { m2 = m1; m1 = v; }
                else if (v > m2) { m2 = v; }
            }
            gsc[g] = m1 + m2;
        }

        unsigned gmask = 0;
#pragma unroll
        for (int p = 0; p < 4; ++p) {
            float best = -1e30f; int bi = 0;
#pragma unroll
            for (int g = 0; g < 8; ++g) {
                const bool taken = (gmask >> g) & 1u;
                if (!taken && gsc[g] > best) { best = gsc[g]; bi = g; }
            }
            gmask |= 1u << bi;
        }

        unsigned long long chosen0 = 0ull, chosen1 = 0ull;
        int   idxs[8];
        float wts[8];
#pragma unroll
        for (int p = 0; p < 8; ++p) {
            float best = -1e30f; int bi = 0;
            for (int e = 0; e < NEXP; ++e) {
                const bool sel = (gmask >> (e >> 4)) & 1u;
                const float v = sel ? scp[e] : 0.0f;
                const bool ch = (e < 64) ? ((chosen0 >> e) & 1ull)
                                         : ((chosen1 >> (e - 64)) & 1ull);
                if (!ch && v > best) { best = v; bi = e; }
            }
            if (bi < 64) chosen0 |= 1ull << bi; else chosen1 |= 1ull << (bi - 64);
            idxs[p] = bi;
            wts[p] = scp[bi] - bias[bi];   // raw sigmoid, ~1e-7 error
        }

        float denom = 0.0f;
#pragma unroll
        for (int p = 0; p < 8; ++p) denom += wts[p];
        denom += 1e-20f;

        const size_t row = (size_t)(tok_base + tid) * 8;
        float* outI = out;
        float* outW = out + (size_t)T_TOKENS * 8;
#pragma unroll
        for (int p = 0; p < 8; ++p) {
            outI[row + p] = (float)idxs[p];
            outW[row + p] = wts[p] / denom;
        }
    }
}

extern "C" void kernel_launch(void* const* d_in, const int* in_sizes, int n_in,
                              void* d_out, int out_size, void* d_ws, size_t ws_size,
                              hipStream_t stream) {
    const float* x    = (const float*)d_in[0];  // [32768, 4096]
    const float* w    = (const float*)d_in[1];  // [128, 4096]
    const float* bias = (const float*)d_in[2];  // [128]
    float* out = (float*)d_out;                 // [idx-as-float | weights]
    short* ws16 = (short*)d_ws;                 // 3 MiB pre-split w image

    presplit_w<<<dim3(NSTAGE * 2 * 4 * 64 / 256), 256, 0, stream>>>(w, ws16);
    glm4_router_mfma<<<dim3(T_TOKENS / TM), 512, 0, stream>>>(x, ws16, bias, out);
}

// Round 15
// 225.642 us; speedup vs baseline: 1.2956x; 1.2956x over previous
//
#include <hip/hip_runtime.h>
#include <math.h>

#define T_TOKENS 32768
#define HIDDEN   4096
#define NEXP     128
#define TM       64
#define BK       32
#define NSTAGE   (HIDDEN / BK)            // 128

// LDS (fp16 elems): [Abuf0 8KB][Abuf1 8KB][Bbuf0 16KB][Bbuf1 16KB] = 48 KiB
// A plane (per buf): 4 row-tiles x 64 lanes x 8 = 2048 elems
// B plane (per buf): 8 col-tiles x 64 lanes x 8 = 4096 elems
#define A_PLANE_SH    2048
#define A_BUF_SH      (2 * A_PLANE_SH)    // 4096
#define B_BASE_SH     (2 * A_BUF_SH)      // 8192
#define B_PLANE_SH    4096
#define B_BUF_SH      (2 * B_PLANE_SH)    // 8192
#define LDS_SHORTS    (B_BASE_SH + 2 * B_BUF_SH)   // 24576 elems = 48 KiB
#define B_BASE_BYTES  (B_BASE_SH * 2)
#define B_BUF_BYTES   (B_BUF_SH * 2)      // 16384
#define SC_STRIDE     129
#define B_CHUNK_BYTES B_BUF_BYTES         // 16 KB per stage
#define WS_BYTES ((size_t)NSTAGE * B_CHUNK_BYTES)  // 2 MiB

typedef _Float16 f16x8 __attribute__((ext_vector_type(8)));
typedef _Float16 f16x4 __attribute__((ext_vector_type(4)));
typedef float f32x4  __attribute__((ext_vector_type(4)));

// fp16 2-term split with denormal-safe normalization:
//   x = h0 + h1*2^-12 + delta, |delta| <= 2^-24 |x|
// h0 flushed to 0 when |fp16(x)| is subnormal (<2^-14) so MFMA never sees
// denormal inputs; the scaled residual plane h1 (x*4096, normal range)
// then carries the full value. h1 itself is normal for all relevant x.
__device__ __forceinline__ void split2(float x, _Float16& h0, _Float16& h1) {
    _Float16 a = (_Float16)x;              // v_cvt_f16_f32, RNE
    float af = (float)a;
    if (__builtin_fabsf(af) < 6.103515625e-05f) { a = (_Float16)0.0f; af = 0.0f; }
    h0 = a;
    h1 = (_Float16)((x - af) * 4096.0f);   // (x-af) exact; *2^12 exact
}

// ---- kernel 1: split w into 2 fp16 planes, fragment-major 16x16x32 image:
// stage s, plane p, tile t, lane l holds w[t*16+(l&15)][s*32+((l>>4)&3)*8+j]
// at ws16[(s*8192) + p*4096 + (t*64+l)*8 + j]. 16 KB/stage chunk = byte-exact
// linear image of the main kernel's B LDS buffer.
__global__ __launch_bounds__(256) void presplit_w(
    const float* __restrict__ w, _Float16* __restrict__ ws16)
{
    const int g = blockIdx.x * 256 + threadIdx.x;    // 65536 total
    const int l = g & 63;
    const int t = (g >> 6) & 7;
    const int s = g >> 9;                            // 0..127
    const int e  = t * 16 + (l & 15);
    const int kb = s * BK + ((l >> 4) & 3) * 8;
    const float* src = w + (size_t)e * HIDDEN + kb;
    float4 v0 = *(const float4*)(src);
    float4 v1 = *(const float4*)(src + 4);
    float vv[8] = {v0.x, v0.y, v0.z, v0.w, v1.x, v1.y, v1.z, v1.w};
    _Float16 h0[8], h1[8];
#pragma unroll
    for (int j = 0; j < 8; ++j) split2(vv[j], h0[j], h1[j]);
    _Float16* dst = ws16 + (size_t)s * 8192 + (t * 64 + l) * 8;
    *(f16x8*)(dst)        = (f16x8){h0[0],h0[1],h0[2],h0[3],h0[4],h0[5],h0[6],h0[7]};
    *(f16x8*)(dst + 4096) = (f16x8){h1[0],h1[1],h1[2],h1[3],h1[4],h1[5],h1[6],h1[7]};
}

// 512 threads = 8 waves; wave owns 32 tok x 32 exp (2x2 of 16x16 tiles).
// 3 split-products: main = x0*w0; corr = x0*w1' + x1'*w0 (both planes
// pre-scaled by 2^12); logit = main + corr*2^-12, folded to fp64 every K=128.
// Sync = R13's verified per-stage __syncthreads; interleave + setprio kept.
__global__ __launch_bounds__(512, 4) void glm4_router_mfma(
    const float* __restrict__ x, const _Float16* __restrict__ wsplit,
    const float* __restrict__ bias, float* __restrict__ out)
{
    __shared__ __align__(16) _Float16 lds[LDS_SHORTS];

    const int tid  = threadIdx.x;
    const int wid  = tid >> 6;
    const int lane = tid & 63;
    const int rt_base = (wid & 1) * 2;      // row-tile base: 0 or 2
    const int ct_base = (wid >> 1) * 2;     // col-tile base: 0,2,4,6
    const int tok_base = blockIdx.x * TM;

    // A staging: thread tid writes f16x4 at elems [tid*4..tid*4+3) per plane.
    // Fragment f=tid>>1: tile=f>>6, l=f&63; row = tile*16+(l&15),
    // k-in-stage = ((l>>4)&3)*8 + (tid&1)*4.
    const int al = (tid >> 1) & 63;
    const int at = tid >> 7;
    const int arow = at * 16 + (al & 15);
    const int akoff = ((al >> 4) & 3) * 8 + (tid & 1) * 4;
    const float* xsrc = x + (size_t)(tok_base + arow) * HIDDEN + akoff;
    const int awr = tid * 4;                // elems, within a plane

    f32x4 mainA[2][2];      // x0*w0
    f32x4 corr[2][2];       // x0*w1' + x1'*w0  (2^12-scaled)
    double accd[2][2][4];   // fp64 running sum
#pragma unroll
    for (int r = 0; r < 2; ++r)
#pragma unroll
        for (int c = 0; c < 2; ++c) {
            mainA[r][c] = (f32x4){0.f, 0.f, 0.f, 0.f};
            corr[r][c]  = (f32x4){0.f, 0.f, 0.f, 0.f};
#pragma unroll
            for (int v = 0; v < 4; ++v) accd[r][c][v] = 0.0;
        }

#define GLDS_B(S, BUF) do {                                                    \
    const char* gsrc_ = (const char*)wsplit + (size_t)(S) * B_CHUNK_BYTES + tid * 16; \
    char* ldst_ = (char*)lds + B_BASE_BYTES + (BUF) * B_BUF_BYTES + tid * 16;  \
    __builtin_amdgcn_global_load_lds(                                          \
        (const __attribute__((address_space(1))) unsigned*)(gsrc_),            \
        (__attribute__((address_space(3))) unsigned*)(ldst_), 16, 0, 0);       \
    __builtin_amdgcn_global_load_lds(                                          \
        (const __attribute__((address_space(1))) unsigned*)(gsrc_ + 8192),     \
        (__attribute__((address_space(3))) unsigned*)(ldst_ + 8192), 16, 0, 0);\
} while (0)

#define SPLIT_A(XV, BUF) do {                                                  \
    _Float16 h0_[4], h1_[4];                                                   \
    split2((XV).x, h0_[0], h1_[0]);                                            \
    split2((XV).y, h0_[1], h1_[1]);                                            \
    split2((XV).z, h0_[2], h1_[2]);                                            \
    split2((XV).w, h0_[3], h1_[3]);                                            \
    _Float16* ab_ = &lds[(BUF) * A_BUF_SH + awr];                              \
    *(f16x4*)(ab_)              = (f16x4){h0_[0], h0_[1], h0_[2], h0_[3]};     \
    *(f16x4*)(ab_ + A_PLANE_SH) = (f16x4){h1_[0], h1_[1], h1_[2], h1_[3]};     \
} while (0)

    // 6 MFMA for one column C: per-acc order main: a0b0; corr: a0b1, a1b0
#define MFMA_COL(C, B0_, B1_) do {                                             \
    _Pragma("unroll")                                                          \
    for (int r = 0; r < 2; ++r) {                                              \
        mainA[r][C] = __builtin_amdgcn_mfma_f32_16x16x32_f16(Af0[r], B0_, mainA[r][C], 0, 0, 0); \
        corr[r][C]  = __builtin_amdgcn_mfma_f32_16x16x32_f16(Af0[r], B1_, corr[r][C], 0, 0, 0);  \
        corr[r][C]  = __builtin_amdgcn_mfma_f32_16x16x32_f16(Af1[r], B0_, corr[r][C], 0, 0, 0);  \
    }                                                                          \
} while (0)

#define BODY(S, BUF, XC, XL) do {                                              \
    GLDS_B((S) + 1, (BUF) ^ 1);                                                \
    {                                                                          \
        int s2_ = (S) + 2; if (s2_ > NSTAGE - 1) s2_ = NSTAGE - 1;             \
        XL = *(const float4*)(xsrc + (size_t)s2_ * BK);                        \
    }                                                                          \
    f16x8 Af0[2], Af1[2];                                                      \
    _Pragma("unroll")                                                          \
    for (int r = 0; r < 2; ++r) {                                              \
        Af0[r] = *(const f16x8*)(&lds[(BUF) * A_BUF_SH                         \
                                      + ((rt_base + r) * 64 + lane) * 8]);     \
        Af1[r] = *(const f16x8*)(&lds[(BUF) * A_BUF_SH + A_PLANE_SH            \
                                      + ((rt_base + r) * 64 + lane) * 8]);     \
    }                                                                          \
    {                                                                          \
        f16x8 B0_ = *(const f16x8*)(&lds[B_BASE_SH + (BUF) * B_BUF_SH          \
                          + ((ct_base + 0) * 64 + lane) * 8]);                 \
        f16x8 B1_ = *(const f16x8*)(&lds[B_BASE_SH + (BUF) * B_BUF_SH          \
                          + B_PLANE_SH + ((ct_base + 0) * 64 + lane) * 8]);    \
        __builtin_amdgcn_s_setprio(1);                                         \
        MFMA_COL(0, B0_, B1_);                                                 \
        __builtin_amdgcn_s_setprio(0);                                         \
    }                                                                          \
    SPLIT_A(XC, (BUF) ^ 1);   /* VALU + ds_write between MFMA clusters */      \
    {                                                                          \
        f16x8 B0_ = *(const f16x8*)(&lds[B_BASE_SH + (BUF) * B_BUF_SH          \
                          + ((ct_base + 1) * 64 + lane) * 8]);                 \
        f16x8 B1_ = *(const f16x8*)(&lds[B_BASE_SH + (BUF) * B_BUF_SH          \
                          + B_PLANE_SH + ((ct_base + 1) * 64 + lane) * 8]);    \
        __builtin_amdgcn_s_setprio(1);                                         \
        MFMA_COL(1, B0_, B1_);                                                 \
        __builtin_amdgcn_s_setprio(0);                                         \
    }                                                                          \
    if (((S) & 3) == 3) {                                                      \
        _Pragma("unroll")                                                      \
        for (int r = 0; r < 2; ++r)                                            \
            _Pragma("unroll")                                                  \
            for (int c = 0; c < 2; ++c) {                                      \
                _Pragma("unroll")                                              \
                for (int v = 0; v < 4; ++v)                                    \
                    accd[r][c][v] += (double)mainA[r][c][v]                    \
                                   + (double)corr[r][c][v] * (1.0 / 4096.0);   \
                mainA[r][c] = (f32x4){0.f, 0.f, 0.f, 0.f};                     \
                corr[r][c]  = (f32x4){0.f, 0.f, 0.f, 0.f};                     \
            }                                                                  \
    }                                                                          \
    __syncthreads();   /* full drain + barrier: verified-correct handoff */    \
} while (0)

    // prologue: fill buf0 with stage 0 (B glds + A split), prefetch x[1]
    float4 xA, xB;
    {
        float4 x0v = *(const float4*)(xsrc);
        GLDS_B(0, 0);
        xA = *(const float4*)(xsrc + BK);   // x[1]
        SPLIT_A(x0v, 0);
    }
    __syncthreads();

    for (int s = 0; s < NSTAGE - 2; s += 2) {
        BODY(s, 0, xA, xB);
        BODY(s + 1, 1, xB, xA);
    }
    BODY(NSTAGE - 2, 0, xA, xB);

    // tail: stage 127 from buf1 (fully staged; drained by the last barrier)
    {
        f16x8 Af0[2], Af1[2];
#pragma unroll
        for (int r = 0; r < 2; ++r) {
            Af0[r] = *(const f16x8*)(&lds[1 * A_BUF_SH
                                          + ((rt_base + r) * 64 + lane) * 8]);
            Af1[r] = *(const f16x8*)(&lds[1 * A_BUF_SH + A_PLANE_SH
                                          + ((rt_base + r) * 64 + lane) * 8]);
        }
#pragma unroll
        for (int c = 0; c < 2; ++c) {
            f16x8 B0_ = *(const f16x8*)(&lds[B_BASE_SH + 1 * B_BUF_SH
                              + ((ct_base + c) * 64 + lane) * 8]);
            f16x8 B1_ = *(const f16x8*)(&lds[B_BASE_SH + 1 * B_BUF_SH
                              + B_PLANE_SH + ((ct_base + c) * 64 + lane) * 8]);
#pragma unroll
            for (int r = 0; r < 2; ++r) {
                mainA[r][c] = __builtin_amdgcn_mfma_f32_16x16x32_f16(Af0[r], B0_, mainA[r][c], 0, 0, 0);
                corr[r][c]  = __builtin_amdgcn_mfma_f32_16x16x32_f16(Af0[r], B1_, corr[r][c], 0, 0, 0);
                corr[r][c]  = __builtin_amdgcn_mfma_f32_16x16x32_f16(Af1[r], B0_, corr[r][c], 0, 0, 0);
            }
        }
        // final fold (S=127 -> (S&3)==3)
#pragma unroll
        for (int r = 0; r < 2; ++r)
#pragma unroll
            for (int c = 0; c < 2; ++c)
#pragma unroll
                for (int v = 0; v < 4; ++v)
                    accd[r][c][v] += (double)mainA[r][c][v]
                                   + (double)corr[r][c][v] * (1.0 / 4096.0);
    }

    // ---- epilogue: logits -> biased scores into LDS overlay (fp32) ----
    __syncthreads();
    float* sc = (float*)lds;                       // [64][129] = 33 KB <= 48 KB
#pragma unroll
    for (int r = 0; r < 2; ++r)
#pragma unroll
        for (int c = 0; c < 2; ++c) {
#pragma unroll
            for (int v = 0; v < 4; ++v) {
                const int tokl = (rt_base + r) * 16 + (lane >> 4) * 4 + v;
                const int e    = (ct_base + c) * 16 + (lane & 15);
                const float lg = (float)accd[r][c][v];
                const float sg = (float)(1.0 / (1.0 + exp(-(double)lg)));
                sc[tokl * SC_STRIDE + e] = sg + bias[e];
            }
        }
    __syncthreads();

    // ---- routing: one lane per token (wave 0) — verified logic ----
    if (tid < TM) {
        const float* scp = sc + tid * SC_STRIDE;

        float gsc[8];
#pragma unroll
        for (int g = 0; g < 8; ++g) {
            float m1 = -1e30f, m2 = -1e30f;
#pragma unroll
            for (int j = 0; j < 16; ++j) {
                const float v = scp[g * 16 + j];
                if (v > m1) { m2 = m1; m1 = v; }
                else if (v > m2) { m2 = v; }
            }
            gsc[g] = m1 + m2;
        }

        unsigned gmask = 0;
#pragma unroll
        for (int p = 0; p < 4; ++p) {
            float best = -1e30f; int bi = 0;
#pragma unroll
            for (int g = 0; g < 8; ++g) {
                const bool taken = (gmask >> g) & 1u;
                if (!taken && gsc[g] > best) { best = gsc[g]; bi = g; }
            }
            gmask |= 1u << bi;
        }

        unsigned long long chosen0 = 0ull, chosen1 = 0ull;
        int   idxs[8];
        float wts[8];
#pragma unroll
        for (int p = 0; p < 8; ++p) {
            float best = -1e30f; int bi = 0;
            for (int e = 0; e < NEXP; ++e) {
                const bool sel = (gmask >> (e >> 4)) & 1u;
                const float v = sel ? scp[e] : 0.0f;
                const bool ch = (e < 64) ? ((chosen0 >> e) & 1ull)
                                         : ((chosen1 >> (e - 64)) & 1ull);
                if (!ch && v > best) { best = v; bi = e; }
            }
            if (bi < 64) chosen0 |= 1ull << bi; else chosen1 |= 1ull << (bi - 64);
            idxs[p] = bi;
            wts[p] = scp[bi] - bias[bi];   // raw sigmoid, ~1e-7 error
        }

        float denom = 0.0f;
#pragma unroll
        for (int p = 0; p < 8; ++p) denom += wts[p];
        denom += 1e-20f;

        const size_t row = (size_t)(tok_base + tid) * 8;
        float* outI = out;
        float* outW = out + (size_t)T_TOKENS * 8;
#pragma unroll
        for (int p = 0; p < 8; ++p) {
            outI[row + p] = (float)idxs[p];
            outW[row + p] = wts[p] / denom;
        }
    }
}

extern "C" void kernel_launch(void* const* d_in, const int* in_sizes, int n_in,
                              void* d_out, int out_size, void* d_ws, size_t ws_size,
                              hipStream_t stream) {
    const float* x    = (const float*)d_in[0];  // [32768, 4096]
    const float* w    = (const float*)d_in[1];  // [128, 4096]
    const float* bias = (const float*)d_in[2];  // [128]
    float* out = (float*)d_out;                 // [idx-as-float | weights]
    _Float16* ws16 = (_Float16*)d_ws;           // 2 MiB pre-split w image

    presplit_w<<<dim3(NSTAGE * 8 * 64 / 256), 256, 0, stream>>>(w, ws16);
    glm4_router_mfma<<<dim3(T_TOKENS / TM), 512, 0, stream>>>(x, ws16, bias, out);
}